// Round 1
// baseline (524.578 us; speedup 1.0000x reference)
//
#include <hip/hip_runtime.h>
#include <hip/hip_bf16.h>

#define NB 8192   // batch
#define ND 1024   // feature dim

typedef __attribute__((ext_vector_type(8))) short bf16x8;
typedef __attribute__((ext_vector_type(4))) float f32x4;

__device__ __forceinline__ void async16(const void* g, void* l) {
  __builtin_amdgcn_global_load_lds(
      (const __attribute__((address_space(1))) void*)g,
      (__attribute__((address_space(3))) void*)l,
      16, 0, 0);
}

__device__ __forceinline__ unsigned short f2bf(float f) {
  union { float f; unsigned u; } a; a.f = f;
  unsigned u = a.u;
  return (unsigned short)((u + 0x7fffu + ((u >> 16) & 1u)) >> 16);  // RNE
}

// ---------------------------------------------------------------------------
// Mask prep: detect bool-byte vs int32 layout, emit float mask.
// If layout is int32 (0/1 values), every byte at (i%4)!=0 is zero in the
// first 8192 bytes (safe to read under both layouts). Random 0/1 bool bytes
// make that impossible.
__global__ void prep_mask(const unsigned char* __restrict__ raw,
                          float* __restrict__ nmask) {
  __shared__ int flag;
  if (threadIdx.x == 0) flag = 0;
  __syncthreads();
  int any = 0;
  for (int i = threadIdx.x; i < NB; i += 256)
    if ((i & 3) != 0 && raw[i] != 0) any = 1;
  if (any) atomicOr(&flag, 1);
  __syncthreads();
  if (flag) {  // 1-byte bool layout
    for (int i = threadIdx.x; i < NB; i += 256)
      nmask[i] = raw[i] ? 1.0f : 0.0f;
  } else {     // int32 layout
    const int* ri = (const int*)raw;
    for (int i = threadIdx.x; i < NB; i += 256)
      nmask[i] = ri[i] ? 1.0f : 0.0f;
  }
}

// ---------------------------------------------------------------------------
// L2-normalize rows of visual/textual feats (f32 in) -> bf16 out.
// grid (NB, 2), block 256. Each thread owns 4 contiguous floats.
__global__ void norm_cast(const float* __restrict__ vis,
                          const float* __restrict__ txt,
                          unsigned short* __restrict__ vb,
                          unsigned short* __restrict__ tb) {
  const float* src = blockIdx.y ? txt : vis;
  unsigned short* dst = blockIdx.y ? tb : vb;
  int row = blockIdx.x;
  int t = threadIdx.x;
  float4 x = ((const float4*)(src + (size_t)row * ND))[t];
  float ss = x.x * x.x + x.y * x.y + x.z * x.z + x.w * x.w;
  #pragma unroll
  for (int m = 32; m; m >>= 1) ss += __shfl_xor(ss, m);
  __shared__ float sred[4];
  if ((t & 63) == 0) sred[t >> 6] = ss;
  __syncthreads();
  float tot = sred[0] + sred[1] + sred[2] + sred[3];
  float inv = 1.0f / fmaxf(sqrtf(tot), 1e-12f);
  ushort4 o;
  o.x = f2bf(x.x * inv); o.y = f2bf(x.y * inv);
  o.z = f2bf(x.z * inv); o.w = f2bf(x.w * inv);
  ((ushort4*)dst)[(size_t)row * (ND / 4) + t] = o;
}

// ---------------------------------------------------------------------------
// Fused GEMM + masked-exp row-sum.
// sim = Vn @ Tn^T (both [NB, ND] row-major, K-contiguous: NT GEMM).
// Block computes a 128x128 sim tile, applies exp2(sim*SCALE)*max(n_i,n_j),
// reduces over the tile's columns, writes partial[bx][row].
// m97 structure: BK=64, 4 waves each doing a 64x64 quadrant of 4x4
// mfma_f32_16x16x32_bf16; global_load_lds width=16 with XOR chunk swizzle
// (swizzle applied on the global-address side: lane l fetches chunk
// (l&7)^(l>>3), so LDS position p of row r holds global chunk p^(r&7) --
// keeps the wave-uniform-base+lane*16 contract intact, kills the stride-128B
// ds_read_b128 bank conflicts).
__global__ __launch_bounds__(256) void gemm_fused(
    const unsigned short* __restrict__ vb, const unsigned short* __restrict__ tb,
    const float* __restrict__ nmask, float* __restrict__ partial) {
  __shared__ unsigned short As[128 * 64];
  __shared__ unsigned short Bs[128 * 64];
  __shared__ float part2[128][2];

  const int bx = blockIdx.x, by = blockIdx.y;
  const int i0 = by * 128, j0 = bx * 128;
  const int t = threadIdx.x;
  const int w = t >> 6;          // wave 0..3
  const int l = t & 63;
  const int quad = l >> 4;
  const int l15 = l & 15;
  const int wm = w >> 1, wn = w & 1;
  const int rw = wm * 64, cw = wn * 64;

  // staging: lane l covers row (l>>3) of its 8-row group, global chunk (l&7)^(l>>3)
  const int lrow = l >> 3;
  const int lchunk = (l & 7) ^ lrow;
  const unsigned short* Ag = vb + (size_t)(i0 + w * 32 + lrow) * ND + lchunk * 8;
  const unsigned short* Bg = tb + (size_t)(j0 + w * 32 + lrow) * ND + lchunk * 8;
  char* AsB = (char*)As + w * 32 * 128;  // bytes: 128 rows x 128 B/row
  char* BsB = (char*)Bs + w * 32 * 128;

  f32x4 acc[4][4] = {};

  for (int kb = 0; kb < ND; kb += 64) {
    #pragma unroll
    for (int q = 0; q < 4; ++q) {
      async16(Ag + kb + q * 8 * ND, AsB + q * 1024);
      async16(Bg + kb + q * 8 * ND, BsB + q * 1024);
    }
    __syncthreads();  // compiler drains vmcnt before s_barrier
    #pragma unroll
    for (int kt = 0; kt < 2; ++kt) {
      bf16x8 a[4], b[4];
      #pragma unroll
      for (int mi = 0; mi < 4; ++mi) {
        int r = rw + mi * 16 + l15;
        int pos = (kt * 4 + quad) ^ (r & 7);
        a[mi] = *(const bf16x8*)&As[r * 64 + pos * 8];
      }
      #pragma unroll
      for (int ni = 0; ni < 4; ++ni) {
        int r = cw + ni * 16 + l15;
        int pos = (kt * 4 + quad) ^ (r & 7);
        b[ni] = *(const bf16x8*)&Bs[r * 64 + pos * 8];
      }
      #pragma unroll
      for (int mi = 0; mi < 4; ++mi)
        #pragma unroll
        for (int ni = 0; ni < 4; ++ni)
          acc[mi][ni] = __builtin_amdgcn_mfma_f32_16x16x32_bf16(
              a[mi], b[ni], acc[mi][ni], 0, 0, 0);
    }
    __syncthreads();
  }

  // Epilogue: val = exp(sim/T)*max(n_row,n_col); row-sum over this block's 128 cols.
  // C/D layout (m89): col = l&15, row = quad*4 + reg.
  const float SCALE = 20.60992915555662f;  // log2(e)/0.07
  float ncol[4];
  #pragma unroll
  for (int ni = 0; ni < 4; ++ni) ncol[ni] = nmask[j0 + cw + ni * 16 + l15];

  #pragma unroll
  for (int mi = 0; mi < 4; ++mi) {
    float nrow[4], rowacc[4] = {0.f, 0.f, 0.f, 0.f};
    #pragma unroll
    for (int r = 0; r < 4; ++r) nrow[r] = nmask[i0 + rw + mi * 16 + quad * 4 + r];
    #pragma unroll
    for (int ni = 0; ni < 4; ++ni) {
      #pragma unroll
      for (int r = 0; r < 4; ++r)
        rowacc[r] += exp2f(acc[mi][ni][r] * SCALE) * fmaxf(nrow[r], ncol[ni]);
    }
    #pragma unroll
    for (int r = 0; r < 4; ++r) {
      float v = rowacc[r];
      v += __shfl_xor(v, 1); v += __shfl_xor(v, 2);
      v += __shfl_xor(v, 4); v += __shfl_xor(v, 8);
      if (l15 == 0) part2[rw + mi * 16 + quad * 4 + r][wn] = v;
    }
  }
  __syncthreads();
  if (t < 128)
    partial[(size_t)bx * NB + i0 + t] = part2[t][0] + part2[t][1];
}

// ---------------------------------------------------------------------------
// loss = mean_i log(sum_c partial[c][i] + 1e-8). 32 blocks x 256 threads.
__global__ void finalize(const float* __restrict__ partial, float* __restrict__ out) {
  int r = blockIdx.x * 256 + threadIdx.x;
  float s = 0.f;
  #pragma unroll 4
  for (int c = 0; c < 64; ++c) s += partial[(size_t)c * NB + r];
  float lg = logf(s + 1e-8f);
  #pragma unroll
  for (int m = 32; m; m >>= 1) lg += __shfl_xor(lg, m);
  __shared__ float sred[4];
  if ((threadIdx.x & 63) == 0) sred[threadIdx.x >> 6] = lg;
  __syncthreads();
  if (threadIdx.x == 0)
    atomicAdd(out, (sred[0] + sred[1] + sred[2] + sred[3]) * (1.0f / NB));
}

// ---------------------------------------------------------------------------
extern "C" void kernel_launch(void* const* d_in, const int* in_sizes, int n_in,
                              void* d_out, int out_size, void* d_ws, size_t ws_size,
                              hipStream_t stream) {
  const float* vis = (const float*)d_in[0];
  const float* txt = (const float*)d_in[1];
  // d_in[2] transport_matrix: unused. d_in[3] clean mask: unused.
  const unsigned char* noisy = (const unsigned char*)d_in[4];
  float* out = (float*)d_out;

  char* ws = (char*)d_ws;
  unsigned short* vb = (unsigned short*)ws;                           // 16 MB bf16
  unsigned short* tb = (unsigned short*)(ws + ((size_t)16 << 20));    // 16 MB bf16
  float* nmask = (float*)(ws + ((size_t)32 << 20));                   // 32 KB
  float* partial = (float*)(ws + ((size_t)32 << 20) + (64 << 10));    // 2 MB

  hipMemsetAsync(d_out, 0, sizeof(float), stream);
  prep_mask<<<1, 256, 0, stream>>>(noisy, nmask);
  norm_cast<<<dim3(NB, 2), 256, 0, stream>>>(vis, txt, vb, tb);
  gemm_fused<<<dim3(NB / 128, NB / 128), 256, 0, stream>>>(vb, tb, nmask, partial);
  finalize<<<NB / 256, 256, 0, stream>>>(partial, out);
}